// Round 30
// baseline (81.484 us; speedup 1.0000x reference)
//
#include <hip/hip_runtime.h>
#include <hip/hip_bf16.h>

#define NROWS 16384   // B*S
#define KD    2048    // D
#define NE    16      // experts
#define ROWS_PER_BLK 64
#define KH    1024    // K-half resident in LDS
#define TPH   16      // tiles of 64 K-floats per half

// v30 = v21 structure with wave->ROW mapping (x-dedup 4x -> 1x).
// Ledger: v21's serial stack = FMA ~14us + TA/VMEM ~13.7us (x read 4x-dup
// by the 4 expert-quartet waves) + latency + HBM. This variant removes the
// duplication: waves differ in rows; lane = (rsub=lane>>3 -> 1 row, seg).
//  - block = 512 thr / 8 waves / 64 rows; grid 256 = 1 block/CU
//  - acc = 16 e x 2 m = 32 floats (v7-proven); ds_read 64/lane/tile but all
//    8-distinct-addr BROADCAST reads (128B/instr) -> LDS pipe ~6.8us
//  - W K-half [32][1024] = 128 KB resident; staged twice; 4 barriers total
//  - epilogue fully in-register per seg-0 lane (complete row) -> no slab
// Output FLOAT32: [262144 probs][32768 ids-as-floats].

__device__ __forceinline__ void gload_lds16(const float* g, float* l) {
    __builtin_amdgcn_global_load_lds(
        (const __attribute__((address_space(1))) void*)g,
        (__attribute__((address_space(3))) void*)l,
        16, 0, 0);
}

__global__ __launch_bounds__(512)
void noisy_router_kernel(const float* __restrict__ x,
                         const float* __restrict__ noise,
                         const float* __restrict__ Wfc,
                         const float* __restrict__ bfc,
                         const float* __restrict__ Wns,
                         const float* __restrict__ bns,
                         float* __restrict__ out)
{
    __shared__ float lds[32 * KH];     // 128 KB: W-half [32 rows][1024]

    const int tid  = threadIdx.x;
    const int lane = tid & 63;
    const int w    = tid >> 6;     // 0..7
    const int seg  = lane & 7;     // 8-float K-slice within tile
    const int rsub = lane >> 3;    // 0..7: row within wave's 8

    const int row = blockIdx.x * ROWS_PER_BLK + w * 8 + rsub;   // 1x coverage

    // staging map (v21-verbatim): instr i (0..15) writes W-stack rows {2i,2i+1};
    // thread tid -> row 2i+(tid>>8), col (tid&255)*4; dest = i*8KB + tid*16B.
    // Rows 0..15 = Wfc, 16..31 = Wns.
    const int wrb  = tid >> 8;             // 0 or 1
    const int scol = (tid & 255) * 4;

    const float* xr = x + (size_t)row * KD + seg * 8;

    float accA[NE], accB[NE];              // 32 floats
    #pragma unroll
    for (int e = 0; e < NE; ++e) { accA[e] = 0.f; accB[e] = 0.f; }

    #pragma unroll 1
    for (int h = 0; h < 2; ++h) {
        const int kbase = h * KH;
        __syncthreads();                       // all reads of prev half done
        {
            const float* srcF = Wfc + (size_t)wrb * KD + kbase + scol;   // i = 0..7
            const float* srcN = Wns + (size_t)wrb * KD + kbase + scol;   // i = 8..15
            #pragma unroll
            for (int i = 0; i < 8; ++i)
                gload_lds16(srcF + (size_t)(2 * i) * KD, lds + i * 2048 + tid * 4);
            #pragma unroll
            for (int i = 0; i < 8; ++i)
                gload_lds16(srcN + (size_t)(2 * i) * KD, lds + (8 + i) * 2048 + tid * 4);
        }
        __syncthreads();                       // W-half staged (vmcnt drained)

        const float* wpF = lds + seg * 8;              // Wfc rows 0..15
        const float* wpN = lds + 16 * KH + seg * 8;    // Wns rows 0..15
        const float* xh  = xr + kbase;

        // ---- 16 tiles, zero barriers; x 1x, W via broadcast ds_read ----
        #pragma unroll 2
        for (int t = 0; t < TPH; ++t) {
            const float4 x0 = *(const float4*)(xh + t * 64);
            const float4 x1 = *(const float4*)(xh + t * 64 + 4);
            #pragma unroll
            for (int e = 0; e < NE; ++e) {
                const float4 a0 = *(const float4*)(wpF + e * KH + t * 64);
                const float4 a1 = *(const float4*)(wpF + e * KH + t * 64 + 4);
                const float4 b0 = *(const float4*)(wpN + e * KH + t * 64);
                const float4 b1 = *(const float4*)(wpN + e * KH + t * 64 + 4);
                float sA = accA[e], sB = accB[e];
                sA = fmaf(x0.x, a0.x, sA); sA = fmaf(x0.y, a0.y, sA);
                sA = fmaf(x0.z, a0.z, sA); sA = fmaf(x0.w, a0.w, sA);
                sA = fmaf(x1.x, a1.x, sA); sA = fmaf(x1.y, a1.y, sA);
                sA = fmaf(x1.z, a1.z, sA); sA = fmaf(x1.w, a1.w, sA);
                sB = fmaf(x0.x, b0.x, sB); sB = fmaf(x0.y, b0.y, sB);
                sB = fmaf(x0.z, b0.z, sB); sB = fmaf(x0.w, b0.w, sB);
                sB = fmaf(x1.x, b1.x, sB); sB = fmaf(x1.y, b1.y, sB);
                sB = fmaf(x1.z, b1.z, sB); sB = fmaf(x1.w, b1.w, sB);
                accA[e] = sA; accB[e] = sB;
            }
        }
    }

    // ---- butterfly over the 8 k-segs (masks 1,2,4: seg bits only) ----
    #pragma unroll
    for (int e = 0; e < NE; ++e) {
        float a = accA[e], b = accB[e];
        a += __shfl_xor(a, 1); a += __shfl_xor(a, 2); a += __shfl_xor(a, 4);
        b += __shfl_xor(b, 1); b += __shfl_xor(b, 2); b += __shfl_xor(b, 4);
        accA[e] = a; accB[e] = b;
    }

    // ---- epilogue fully in-register: seg-0 lane owns its complete row ----
    if (seg == 0) {
        const size_t grow = (size_t)row;
        const float* nzp = noise + grow * NE;

        float m1 = -1e30f, m2 = -1e30f;
        int i1 = 0, i2 = 0;
        #pragma unroll
        for (int j = 0; j < NE; ++j) {
            const float z  = accB[j] + bns[j];
            const float sp = fmaxf(z, 0.f) + log1pf(expf(-fabsf(z)));  // jax softplus
            const float v  = fmaf(nzp[j], sp, accA[j] + bfc[j]);
            if (v > m1)      { m2 = m1; i2 = i1; m1 = v; i1 = j; }     // ties -> lower idx
            else if (v > m2) { m2 = v;  i2 = j; }
        }
        const float e2  = expf(m2 - m1);
        const float inv = 1.f / (1.f + e2);

        float* po = out + grow * NE;
        #pragma unroll
        for (int j = 0; j < NE; ++j) {
            po[j] = (j == i1) ? inv : ((j == i2) ? e2 * inv : 0.f);
        }
        float* pi = out + (size_t)NROWS * NE + grow * 2;
        pi[0] = (float)i1;
        pi[1] = (float)i2;
    }
}

extern "C" void kernel_launch(void* const* d_in, const int* in_sizes, int n_in,
                              void* d_out, int out_size, void* d_ws, size_t ws_size,
                              hipStream_t stream)
{
    const float* x     = (const float*)d_in[0];
    const float* noise = (const float*)d_in[1];
    const float* Wfc   = (const float*)d_in[2];
    const float* bfc   = (const float*)d_in[3];
    const float* Wns   = (const float*)d_in[4];
    const float* bns   = (const float*)d_in[5];
    float* out = (float*)d_out;

    noisy_router_kernel<<<NROWS / ROWS_PER_BLK, 512, 0, stream>>>(
        x, noise, Wfc, bfc, Wns, bns, out);
}

// Round 32
// 45.813 us; speedup vs baseline: 1.7786x; 1.7786x over previous
//
#include <hip/hip_runtime.h>
#include <hip/hip_bf16.h>

#define NROWS 16384   // B*S
#define KD    2048    // D
#define NE    16      // experts
#define ROWS_PER_BLK 64
#define KH    1024    // K-half resident in LDS
#define TPH   16      // tiles of 64 K-floats per half

// v31b = v21 (barrier-free champion, 48.7us) with PACKED fp32 FMA core.
// (v31 failed to compile: stray duplicate decl. Fixed -- no logic change.)
// Ledger (rocprof ~2x dur inflation): VALU-active ~46% of timed time ->
// issue-bound. v_pk_fma_f32 (VOP3P) does 2 fp32 FMAs/instr; core on
// ext_vector_type(2) + __builtin_elementwise_fma. FMA instrs/tile: 256->128.
//  - block = 512 thr / 8 waves / 64 rows; grid 256 = 1 block/CU
//  - wave w -> (expert-quartet eq=w&3, row-half rh=w>>2); x-dup 4x
//  - acc = 32 fp32 in 16+16 v2f (same VGPR count); W K-half resident; 3 barriers
// Output FLOAT32: [262144 probs][32768 ids-as-floats].

typedef float v2f __attribute__((ext_vector_type(2)));

__device__ __forceinline__ void gload_lds16(const float* g, float* l) {
    __builtin_amdgcn_global_load_lds(
        (const __attribute__((address_space(1))) void*)g,
        (__attribute__((address_space(3))) void*)l,
        16, 0, 0);
}

__global__ __launch_bounds__(512)
void noisy_router_kernel(const float* __restrict__ x,
                         const float* __restrict__ noise,
                         const float* __restrict__ Wfc,
                         const float* __restrict__ bfc,
                         const float* __restrict__ Wns,
                         const float* __restrict__ bns,
                         float* __restrict__ out)
{
    // [0, 32768): W-half [32 rows][1024];  [32768, 34880): epilogue slab [64][33]
    __shared__ float lds[32 * KH + ROWS_PER_BLK * 33];   // 139.5 KB

    const int tid  = threadIdx.x;
    const int lane = tid & 63;
    const int w    = tid >> 6;     // 0..7
    const int eq   = w & 3;        // expert quartet 0..3
    const int rh   = w >> 2;       // row half 0..1
    const int seg  = lane & 7;
    const int rgrp = lane >> 3;

    const int rowbase = blockIdx.x * ROWS_PER_BLK + rh * 32 + rgrp * 4;

    // staging map: instr i (0..15) writes W-stack rows {2i, 2i+1}:
    // thread tid -> row 2i + (tid>>8), col (tid&255)*4; dest = i*8KB + tid*16B
    // (uniform base + lane*16: legal form). Rows 0..15 = Wfc, 16..31 = Wns.
    const int wrb  = tid >> 8;             // 0 or 1
    const int scol = (tid & 255) * 4;

    const float* xb = x + (size_t)rowbase * KD + seg * 8;

    v2f acA[4][4], acB[4][4];              // 32 fp32 total accumulator state
    #pragma unroll
    for (int j = 0; j < 4; ++j)
        #pragma unroll
        for (int e = 0; e < 4; ++e) { acA[j][e] = (v2f)(0.f); acB[j][e] = (v2f)(0.f); }

    #pragma unroll 1
    for (int h = 0; h < 2; ++h) {
        const int kbase = h * KH;
        __syncthreads();                       // all reads of prev half done
        {
            const float* srcF = Wfc + (size_t)wrb * KD + kbase + scol;   // i = 0..7
            const float* srcN = Wns + (size_t)wrb * KD + kbase + scol;   // i = 8..15
            #pragma unroll
            for (int i = 0; i < 8; ++i)
                gload_lds16(srcF + (size_t)(2 * i) * KD, lds + i * 2048 + tid * 4);
            #pragma unroll
            for (int i = 0; i < 8; ++i)
                gload_lds16(srcN + (size_t)(2 * i) * KD, lds + (8 + i) * 2048 + tid * 4);
        }
        __syncthreads();                       // W-half staged (vmcnt drained)

        const float* wp0 = lds + (eq * 4) * KH + seg * 8;        // Wfc rows
        const float* wp1 = lds + (16 + eq * 4) * KH + seg * 8;   // Wns rows
        const float* xh  = xb + kbase;

        // ---- 16 tiles, ZERO barriers; packed-fp32 FMA core ----
        #pragma unroll 2
        for (int t = 0; t < TPH; ++t) {
            v2f xv[4][4];                      // 4 rows x 4 k-pairs
            #pragma unroll
            for (int j = 0; j < 4; ++j) {
                const float4 x0 = *(const float4*)(xh + (size_t)j * KD + t * 64);
                const float4 x1 = *(const float4*)(xh + (size_t)j * KD + t * 64 + 4);
                xv[j][0] = (v2f){x0.x, x0.y}; xv[j][1] = (v2f){x0.z, x0.w};
                xv[j][2] = (v2f){x1.x, x1.y}; xv[j][3] = (v2f){x1.z, x1.w};
            }
            #pragma unroll
            for (int e = 0; e < 4; ++e) {
                const float4 a0 = *(const float4*)(wp0 + e * KH + t * 64);
                const float4 a1 = *(const float4*)(wp0 + e * KH + t * 64 + 4);
                const float4 b0 = *(const float4*)(wp1 + e * KH + t * 64);
                const float4 b1 = *(const float4*)(wp1 + e * KH + t * 64 + 4);
                const v2f ap0 = (v2f){a0.x, a0.y}, ap1 = (v2f){a0.z, a0.w};
                const v2f ap2 = (v2f){a1.x, a1.y}, ap3 = (v2f){a1.z, a1.w};
                const v2f bp0 = (v2f){b0.x, b0.y}, bp1 = (v2f){b0.z, b0.w};
                const v2f bp2 = (v2f){b1.x, b1.y}, bp3 = (v2f){b1.z, b1.w};
                #pragma unroll
                for (int j = 0; j < 4; ++j) {
                    v2f sA = acA[j][e], sB = acB[j][e];
                    sA = __builtin_elementwise_fma(xv[j][0], ap0, sA);
                    sA = __builtin_elementwise_fma(xv[j][1], ap1, sA);
                    sA = __builtin_elementwise_fma(xv[j][2], ap2, sA);
                    sA = __builtin_elementwise_fma(xv[j][3], ap3, sA);
                    sB = __builtin_elementwise_fma(xv[j][0], bp0, sB);
                    sB = __builtin_elementwise_fma(xv[j][1], bp1, sB);
                    sB = __builtin_elementwise_fma(xv[j][2], bp2, sB);
                    sB = __builtin_elementwise_fma(xv[j][3], bp3, sB);
                    acA[j][e] = sA; acB[j][e] = sB;
                }
            }
        }
    }

    // ---- horizontal fold + butterfly over the 8 k-segs ----
    float accA[4][4], accB[4][4];
    #pragma unroll
    for (int j = 0; j < 4; ++j)
        #pragma unroll
        for (int e = 0; e < 4; ++e) {
            float a = acA[j][e].x + acA[j][e].y;
            float b = acB[j][e].x + acB[j][e].y;
            a += __shfl_xor(a, 1); a += __shfl_xor(a, 2); a += __shfl_xor(a, 4);
            b += __shfl_xor(b, 1); b += __shfl_xor(b, 2); b += __shfl_xor(b, 4);
            accA[j][e] = a; accB[j][e] = b;
        }

    __syncthreads();                  // all W reads done
    float* const slab = lds + 32 * KH;   // [64 rows][stride 33]

    if (seg == 0) {                   // each wave owns complete (row, e-quartet) outs
        #pragma unroll
        for (int j = 0; j < 4; ++j) {
            float* dst = slab + (rh * 32 + rgrp * 4 + j) * 33 + eq * 4;
            #pragma unroll
            for (int e = 0; e < 4; ++e) { dst[e] = accA[j][e]; dst[16 + e] = accB[j][e]; }
        }
    }
    __syncthreads();

    // ---- per-row epilogue: softplus noise, top-2, sparse softmax ----
    if (tid < ROWS_PER_BLK) {
        const int r = tid;
        const float* rowp = slab + r * 33;
        const size_t grow = (size_t)blockIdx.x * ROWS_PER_BLK + r;
        const float* nzp = noise + grow * NE;

        float m1 = -1e30f, m2 = -1e30f;
        int i1 = 0, i2 = 0;
        #pragma unroll
        for (int j = 0; j < NE; ++j) {
            const float z  = rowp[16 + j] + bns[j];
            const float sp = fmaxf(z, 0.f) + log1pf(expf(-fabsf(z)));  // jax softplus
            const float v  = fmaf(nzp[j], sp, rowp[j] + bfc[j]);
            if (v > m1)      { m2 = m1; i2 = i1; m1 = v; i1 = j; }     // ties -> lower idx
            else if (v > m2) { m2 = v;  i2 = j; }
        }
        const float e2  = expf(m2 - m1);
        const float inv = 1.f / (1.f + e2);

        float* po = out + grow * NE;
        #pragma unroll
        for (int j = 0; j < NE; ++j) {
            po[j] = (j == i1) ? inv : ((j == i2) ? e2 * inv : 0.f);
        }
        float* pi = out + (size_t)NROWS * NE + grow * 2;
        pi[0] = (float)i1;
        pi[1] = (float)i2;
    }
}

extern "C" void kernel_launch(void* const* d_in, const int* in_sizes, int n_in,
                              void* d_out, int out_size, void* d_ws, size_t ws_size,
                              hipStream_t stream)
{
    const float* x     = (const float*)d_in[0];
    const float* noise = (const float*)d_in[1];
    const float* Wfc   = (const float*)d_in[2];
    const float* bfc   = (const float*)d_in[3];
    const float* Wns   = (const float*)d_in[4];
    const float* bns   = (const float*)d_in[5];
    float* out = (float*)d_out;

    noisy_router_kernel<<<NROWS / ROWS_PER_BLK, 512, 0, stream>>>(
        x, noise, Wfc, bfc, Wns, bns, out);
}